// Round 1
// 535.956 us; speedup vs baseline: 1.8694x; 1.8694x over previous
//
#include <hip/hip_runtime.h>
#include <cstddef>

#define LL 512
#define CC 32
#define NF1D 46
#define NF2D 44
#define KK 64
#define LBLK 16

// ---------------- tiny zero kernel (stats re-init each call) ----------------
__global__ void zero_kernel(float* __restrict__ p, int n) {
    int i = blockIdx.x * blockDim.x + threadIdx.x;
    if (i < n) p[i] = 0.0f;
}

// ---------------- tower: conv1 stage (resblock rb) ----------------
__global__ __launch_bounds__(256) void conv_a_kernel(
    const float* __restrict__ t1d, const float* __restrict__ w1d,
    const float* __restrict__ b1d, const float* __restrict__ xprev,
    const float* __restrict__ zg, const float* __restrict__ stats_prev,
    const float* __restrict__ cw, float* __restrict__ xout,
    float* __restrict__ yg, float* __restrict__ stats_y, int first)
{
    __shared__ float xs[18 * 32];
    __shared__ float wl[3072];
    __shared__ float mc[32], vc[32];
    __shared__ float ssum[32], ssq[32];
    int tid = threadIdx.x;
    int bt = blockIdx.x >> 5;
    int l0 = (blockIdx.x & 31) * LBLK;

    if (tid < 32) {
        ssum[tid] = 0.f; ssq[tid] = 0.f;
        if (!first) {
            float s = stats_prev[bt * 64 + tid * 2];
            float q = stats_prev[bt * 64 + tid * 2 + 1];
            float m = s * (1.0f / 512.0f);
            float v = q * (1.0f / 512.0f) - m * m;
            mc[tid] = m;
            vc[tid] = rsqrtf(v + 1e-5f);
        }
    }
    for (int t = tid; t < 3072; t += 256) {
        int oc = t / 96, rem = t - oc * 96;
        wl[rem * 32 + oc] = cw[t];
    }
    __syncthreads();

    for (int idx = tid; idx < 18 * 32; idx += 256) {
        int c = idx & 31, ll = idx >> 5;
        int l = l0 - 1 + ll;
        float val = 0.f;
        if (l >= 0 && l < LL) {
            if (first) {
                const float* tr = t1d + (size_t)(bt * LL + l) * NF1D;
                const float* wr = w1d + c * NF1D;
                float a = b1d[c];
                for (int f = 0; f < NF1D; ++f) a = fmaf(tr[f], wr[f], a);
                val = a;
            } else {
                int g = (bt * LL + l) * CC + c;
                float a = xprev[g] + (zg[g] - mc[c]) * vc[c];
                val = a > 0.f ? a : (expf(a) - 1.f);
            }
            if (ll >= 1 && ll <= LBLK) xout[(bt * LL + l) * CC + c] = val;
        }
        xs[ll * 32 + c] = val;
    }
    __syncthreads();

    int oc = tid & 31;
    int lpb = tid >> 5;
    for (int p = 0; p < 2; ++p) {
        int lpos = p * 8 + lpb;
        float acc = 0.f;
        for (int icn = 0; icn < CC; ++icn) {
            float x0 = xs[lpos * 32 + icn];
            float x1 = xs[(lpos + 1) * 32 + icn];
            float x2 = xs[(lpos + 2) * 32 + icn];
            acc = fmaf(x0, wl[(icn * 3 + 0) * 32 + oc], acc);
            acc = fmaf(x1, wl[(icn * 3 + 1) * 32 + oc], acc);
            acc = fmaf(x2, wl[(icn * 3 + 2) * 32 + oc], acc);
        }
        yg[(bt * LL + l0 + lpos) * CC + oc] = acc;
        atomicAdd(&ssum[oc], acc);
        atomicAdd(&ssq[oc], acc * acc);
    }
    __syncthreads();
    if (tid < 32) {
        atomicAdd(&stats_y[bt * 64 + tid * 2], ssum[tid]);
        atomicAdd(&stats_y[bt * 64 + tid * 2 + 1], ssq[tid]);
    }
}

// ---------------- tower: conv2 stage ----------------
__global__ __launch_bounds__(256) void conv_b_kernel(
    const float* __restrict__ yin, const float* __restrict__ stats_y,
    const float* __restrict__ cw, float* __restrict__ zg,
    float* __restrict__ stats_z)
{
    __shared__ float xs[18 * 32];
    __shared__ float wl[3072];
    __shared__ float mc[32], vc[32];
    __shared__ float ssum[32], ssq[32];
    int tid = threadIdx.x;
    int bt = blockIdx.x >> 5;
    int l0 = (blockIdx.x & 31) * LBLK;

    if (tid < 32) {
        ssum[tid] = 0.f; ssq[tid] = 0.f;
        float s = stats_y[bt * 64 + tid * 2];
        float q = stats_y[bt * 64 + tid * 2 + 1];
        float m = s * (1.0f / 512.0f);
        float v = q * (1.0f / 512.0f) - m * m;
        mc[tid] = m;
        vc[tid] = rsqrtf(v + 1e-5f);
    }
    for (int t = tid; t < 3072; t += 256) {
        int oc = t / 96, rem = t - oc * 96;
        wl[rem * 32 + oc] = cw[t];
    }
    __syncthreads();

    for (int idx = tid; idx < 18 * 32; idx += 256) {
        int c = idx & 31, ll = idx >> 5;
        int l = l0 - 1 + ll;
        float val = 0.f;
        if (l >= 0 && l < LL) {
            int g = (bt * LL + l) * CC + c;
            float a = (yin[g] - mc[c]) * vc[c];
            val = a > 0.f ? a : (expf(a) - 1.f);
        }
        xs[ll * 32 + c] = val;
    }
    __syncthreads();

    int oc = tid & 31;
    int lpb = tid >> 5;
    for (int p = 0; p < 2; ++p) {
        int lpos = p * 8 + lpb;
        float acc = 0.f;
        for (int icn = 0; icn < CC; ++icn) {
            float x0 = xs[lpos * 32 + icn];
            float x1 = xs[(lpos + 1) * 32 + icn];
            float x2 = xs[(lpos + 2) * 32 + icn];
            acc = fmaf(x0, wl[(icn * 3 + 0) * 32 + oc], acc);
            acc = fmaf(x1, wl[(icn * 3 + 1) * 32 + oc], acc);
            acc = fmaf(x2, wl[(icn * 3 + 2) * 32 + oc], acc);
        }
        zg[(bt * LL + l0 + lpos) * CC + oc] = acc;
        atomicAdd(&ssum[oc], acc);
        atomicAdd(&ssq[oc], acc * acc);
    }
    __syncthreads();
    if (tid < 32) {
        atomicAdd(&stats_z[bt * 64 + tid * 2], ssum[tid]);
        atomicAdd(&stats_z[bt * 64 + tid * 2 + 1], ssq[tid]);
    }
}

// ---------------- finalize: emb -> leftpe/rightpe (pe + bias folded) ----------------
__global__ __launch_bounds__(256) void finalize_kernel(
    const float* __restrict__ xg, const float* __restrict__ zg,
    const float* __restrict__ stats7, const float* __restrict__ proj_w,
    const float* __restrict__ proj_b, float* __restrict__ leftpe,
    float* __restrict__ rightpe)
{
    __shared__ float emb[8 * 32];
    int tid = threadIdx.x;
    int r0 = blockIdx.x * 8;
    {
        int rl = tid >> 5, c = tid & 31;
        int r = r0 + rl;
        int bt = r >> 9;
        float s = stats7[bt * 64 + c * 2];
        float q = stats7[bt * 64 + c * 2 + 1];
        float m = s * (1.0f / 512.0f);
        float v = q * (1.0f / 512.0f) - m * m;
        float inv = rsqrtf(v + 1e-5f);
        float a = xg[r * 32 + c] + (zg[r * 32 + c] - m) * inv;
        emb[rl * 32 + c] = a > 0.f ? a : (expf(a) - 1.f);
    }
    __syncthreads();
    const float C16 = 0.5756462732485115f;  // ln(10000)/16
    for (int p = 0; p < 2; ++p) {
        int idx = p * 256 + tid;
        int rl = idx >> 6, o = idx & 63;
        int r = r0 + rl;
        int bt = r >> 9, l = r & 511;
        const float* pw = proj_w + o * 109;
        float lacc = 0.f, racc = proj_b[o];
        for (int c = 0; c < CC; ++c) {
            float e = emb[rl * 32 + c];
            lacc = fmaf(e, pw[NF2D + c], lacc);
            racc = fmaf(e, pw[NF2D + CC + c], racc);
        }
        if (bt == 0) {
            int k = o & 31;
            float fl = (float)l;
            float pe;
            if (k < 16) pe = sinf(fl * expf(-(float)k * C16));
            else        pe = cosf(fl * expf(-(float)(k - 16) * C16));
            if (o < 32) lacc += pe; else racc += pe;
        }
        leftpe[r * 64 + o] = lacc;
        rightpe[r * 64 + o] = racc;
    }
}

// ---------------- main pair kernel: per-block GEMM, 8x8 register tiles ----------------
// block = (bt,i). out[512 j][64 o] = x[512 j][44 f] . Wt[44 f][64 o] + lpe + rpe + sep*wsep.
// Each wave owns 128 j (2 tiles of 64). x rows streamed per-lane-contiguous from HBM
// (coalescing-friendly, 11 KB unique bytes in flight per wave), transposed into a
// wave-private LDS tile; W^T staged once per block. Lane grid 8x8, per-lane 8j x 8o
// accumulator -> 64 independent FMA chains per lane (ILP covers LDS-capped occupancy).
__global__ __launch_bounds__(256, 2) void pair_kernel(
    const float* __restrict__ t2d, const float* __restrict__ proj_w,
    const float* __restrict__ leftpe, const float* __restrict__ rightpe,
    float* __restrict__ out)
{
    __shared__ float Wt[NF2D * 64];       // Wt[k*64 + o]
    __shared__ float aux[128];            // [0:64) wsep, [64:128) lpe
    __shared__ float xT[4][NF2D * 64];    // per-wave transposed x tile: [k*64 + j]

    const int tid  = threadIdx.x;
    const int blk  = blockIdx.x;          // bt*512 + i
    const int bt   = blk >> 9;
    const int i    = blk & 511;
    const int wave = tid >> 6;
    const int lane = tid & 63;
    const int jg   = lane >> 3;           // 0..7: j-group
    const int og   = lane & 7;            // 0..7: o-group

    // stage W^T (transposed rows of proj_w[:, :44]) + wsep + lpe (one-time, L2-hot)
    for (int idx = tid; idx < NF2D * 64; idx += 256) {
        int o = idx & 63, k = idx >> 6;
        Wt[idx] = proj_w[o * 109 + k];
    }
    if (tid < 64) {
        aux[tid]      = proj_w[tid * 109 + 108];   // wsep
        aux[64 + tid] = leftpe[blk * 64 + tid];    // lpe (pe folded for bt==0)
    }
    __syncthreads();

    // hoist per-lane epilogue constants for this lane's 8 output cols
    float lp[8], wv[8];
#pragma unroll
    for (int c = 0; c < 8; ++c) {
        lp[c] = aux[64 + og * 8 + c];
        wv[c] = aux[og * 8 + c];
    }

    float* xTw = xT[wave];
    const int jbase = wave * 128;
    const float* xsrc = t2d + ((size_t)blk * LL + jbase + lane) * NF2D;  // 176B rows, 16B aligned

    // prefetch tile 0 (lane = row j0+lane, 11 x float4 per-lane contiguous)
    float4 xv[11];
#pragma unroll
    for (int q = 0; q < 11; ++q) xv[q] = ((const float4*)xsrc)[q];

#pragma unroll
    for (int t = 0; t < 2; ++t) {
        // transpose current tile regs -> LDS (lanes stride-1 in j: conflict-free)
#pragma unroll
        for (int q = 0; q < 11; ++q) {
            xTw[(4 * q + 0) * 64 + lane] = xv[q].x;
            xTw[(4 * q + 1) * 64 + lane] = xv[q].y;
            xTw[(4 * q + 2) * 64 + lane] = xv[q].z;
            xTw[(4 * q + 3) * 64 + lane] = xv[q].w;
        }
        // prefetch next tile into registers while computing this one
        float4 nv[11];
        if (t == 0) {
            const float4* ns = (const float4*)(xsrc + (size_t)64 * NF2D);
#pragma unroll
            for (int q = 0; q < 11; ++q) nv[q] = ns[q];
        }

        float acc[8][8];
#pragma unroll
        for (int r = 0; r < 8; ++r)
#pragma unroll
            for (int c = 0; c < 8; ++c) acc[r][c] = 0.f;

        // GEMM microkernel: per k, 4 ds_read_b128 feed 64 FMAs
#pragma unroll 4
        for (int k = 0; k < NF2D; ++k) {
            float4 a0 = *(const float4*)&xTw[k * 64 + jg * 8];
            float4 a1 = *(const float4*)&xTw[k * 64 + jg * 8 + 4];
            float4 b0 = *(const float4*)&Wt[k * 64 + og * 8];
            float4 b1 = *(const float4*)&Wt[k * 64 + og * 8 + 4];
            float av[8] = {a0.x, a0.y, a0.z, a0.w, a1.x, a1.y, a1.z, a1.w};
            float bv[8] = {b0.x, b0.y, b0.z, b0.w, b1.x, b1.y, b1.z, b1.w};
#pragma unroll
            for (int r = 0; r < 8; ++r)
#pragma unroll
                for (int c = 0; c < 8; ++c)
                    acc[r][c] = fmaf(av[r], bv[c], acc[r][c]);
        }

        // epilogue: + lpe + rpe + sep*wsep, coalesced stores
        const int j0 = jbase + t * 64 + jg * 8;
#pragma unroll
        for (int r = 0; r < 8; ++r) {
            int j = j0 + r;
            int d = i - j; d = d < 0 ? -d : d;
            float sv = __logf((float)(d + 1));
            const float4* rp = (const float4*)(rightpe + ((size_t)(bt * LL + j)) * 64 + og * 8);
            float4 r0 = rp[0], r1 = rp[1];
            float4 o0, o1;
            o0.x = acc[r][0] + lp[0] + r0.x + sv * wv[0];
            o0.y = acc[r][1] + lp[1] + r0.y + sv * wv[1];
            o0.z = acc[r][2] + lp[2] + r0.z + sv * wv[2];
            o0.w = acc[r][3] + lp[3] + r0.w + sv * wv[3];
            o1.x = acc[r][4] + lp[4] + r1.x + sv * wv[4];
            o1.y = acc[r][5] + lp[5] + r1.y + sv * wv[5];
            o1.z = acc[r][6] + lp[6] + r1.z + sv * wv[6];
            o1.w = acc[r][7] + lp[7] + r1.w + sv * wv[7];
            float4* op = (float4*)(out + ((size_t)blk * LL + j) * 64 + og * 8);
            op[0] = o0;
            op[1] = o1;
        }

        if (t == 0) {
#pragma unroll
            for (int q = 0; q < 11; ++q) xv[q] = nv[q];
        }
    }
}

extern "C" void kernel_launch(void* const* d_in, const int* in_sizes, int n_in,
                              void* d_out, int out_size, void* d_ws, size_t ws_size,
                              hipStream_t stream) {
    const float* t1d = (const float*)d_in[0];
    const float* t2d = (const float*)d_in[1];
    const float* w1d = (const float*)d_in[2];
    const float* b1d = (const float*)d_in[3];
    const float* c1w = (const float*)d_in[4];
    const float* c2w = (const float*)d_in[5];
    const float* pw  = (const float*)d_in[6];
    const float* pb  = (const float*)d_in[7];
    float* out = (float*)d_out;
    float* ws = (float*)d_ws;

    // workspace layout (floats)
    float* xg_a  = ws;                 // 4*512*32 = 65536
    float* xg_b  = ws + 65536;
    float* yg    = ws + 131072;
    float* zg    = ws + 196608;
    float* stats = ws + 262144;        // 8 stages * 256
    float* lpe   = ws + 264192;        // 4*512*64 = 131072
    float* rpe   = ws + 395264;

    zero_kernel<<<8, 256, 0, stream>>>(stats, 2048);

    for (int rb = 0; rb < 4; ++rb) {
        float* sy = stats + (2 * rb) * 256;
        float* sz = stats + (2 * rb + 1) * 256;
        const float* sprev = (rb == 0) ? stats : stats + (2 * rb - 1) * 256;
        const float* xprev = (rb & 1) ? xg_a : xg_b;
        float* xout = (rb & 1) ? xg_b : xg_a;
        if (rb == 1 || rb == 3) { xprev = xg_a; xout = xg_b; }
        else if (rb == 2)        { xprev = xg_b; xout = xg_a; }
        conv_a_kernel<<<128, 256, 0, stream>>>(t1d, w1d, b1d, xprev, zg, sprev,
                                               c1w + rb * 3072, xout, yg, sy,
                                               rb == 0 ? 1 : 0);
        conv_b_kernel<<<128, 256, 0, stream>>>(yg, sy, c2w + rb * 3072, zg, sz);
    }
    finalize_kernel<<<256, 256, 0, stream>>>(xg_b, zg, stats + 7 * 256, pw, pb,
                                             lpe, rpe);
    pair_kernel<<<2048, 256, 0, stream>>>(t2d, pw, lpe, rpe, out);
}